// Round 4
// baseline (159.818 us; speedup 1.0000x reference)
//
#include <hip/hip_runtime.h>

// inputs: [M=4096, N=16384] fp32 logits; targets: [M] int32; k = int(0.01*(N-1)) = 163
#define M        4096
#define N        16384
#define K_SEL    163
#define DELTA_W  5.0f
#define NT       256
#define CAP      512           // per-row global candidate capacity (mean 373, sd 19)
#define SCALE    4096.0f       // fixed-point scale: order-independent sum, err ~1e-4 << 0.47
#define THRESH   2.0f          // E[count(x>=2)] = 373 per row; 11 sigma above K_SEL

// Order-preserving float<->uint32 key (ascending float <-> ascending key)
__device__ __forceinline__ unsigned f2key(float x) {
    unsigned u = __float_as_uint(x);
    return u ^ ((unsigned)((int)u >> 31) | 0x80000000u);
}
__device__ __forceinline__ float key2f(unsigned k) {
    unsigned u = k ^ (~(unsigned)((int)k >> 31) | 0x80000000u);
    return __uint_as_float(u);
}
__device__ __forceinline__ void wave_lgkm_wait() {
    asm volatile("s_waitcnt lgkmcnt(0)" ::: "memory");
}

// ---------------- Kernel A: barrier-free streaming candidate filter ----------------
__global__ __launch_bounds__(NT) void stream_candidates(
    const float* __restrict__ inp, const int* __restrict__ tgt,
    unsigned* __restrict__ cnt, unsigned* __restrict__ list)
{
    const int row = blockIdx.x;
    const int tid = threadIdx.x;
    const float* rp = inp + (size_t)row * N;
    const int target = tgt[row];
    unsigned* rl = list + (size_t)row * CAP;
    const float4* rp4 = reinterpret_cast<const float4*>(rp);

    #pragma unroll
    for (int b = 0; b < 4; ++b) {
        float4 v[4];
        #pragma unroll
        for (int u = 0; u < 4; ++u) v[u] = rp4[(b * 4 + u) * NT + tid];  // 4 loads in flight
        #pragma unroll
        for (int u = 0; u < 4; ++u) {
            const int base = ((b * 4 + u) * NT + tid) * 4;
            #pragma unroll
            for (int j = 0; j < 4; ++j) {
                float x = (j == 0) ? v[u].x : (j == 1) ? v[u].y : (j == 2) ? v[u].z : v[u].w;
                if (x >= THRESH && (base + j) != target) {
                    unsigned idx = atomicAdd(&cnt[row], 1u);  // wave-uniform addr -> 1 atomic/wave
                    if (idx < CAP) rl[idx] = f2key(x);
                }
            }
        }
    }
}

// ---------------- Kernel B: wave-per-row radix select, ZERO __syncthreads ----------------
__global__ __launch_bounds__(NT) void select_and_loss(
    const float* __restrict__ inp, const int* __restrict__ tgt,
    const unsigned* __restrict__ cnt, const unsigned* __restrict__ list,
    float* __restrict__ row_loss)
{
    __shared__ unsigned hist_all[4][256];              // 1 KiB per wave, wave-private
    const int lane = threadIdx.x & 63;
    const int wv   = threadIdx.x >> 6;
    const int row  = blockIdx.x * 4 + wv;
    unsigned* hist = hist_all[wv];
    const float* rp = inp + (size_t)row * N;
    const int target = tgt[row];
    const unsigned CHI = cnt[row];

    unsigned prefix = 0u, kr = K_SEL;

    if (CHI >= K_SEL && CHI <= CAP) {
        // ---- main path: select over the <=512-entry candidate list ----
        const unsigned* gl = list + (size_t)row * CAP;
        unsigned keys[8];
        #pragma unroll
        for (int it = 0; it < 8; ++it) {
            unsigned i = lane + it * 64u;
            keys[it] = (i < CHI) ? gl[i] : 0u;         // pad with min-key (never selected)
        }
        for (int pass = 0; pass < 4; ++pass) {
            *reinterpret_cast<uint4*>(&hist[lane * 4]) = make_uint4(0, 0, 0, 0);
            wave_lgkm_wait();
            const int shift = 24 - 8 * pass;
            #pragma unroll
            for (int it = 0; it < 8; ++it) {
                unsigned k = keys[it];
                bool m = (lane + it * 64u < CHI) &&
                         (pass == 0 || (k >> (shift + 8)) == prefix);
                if (m) atomicAdd(&hist[(k >> shift) & 0xFFu], 1u);
            }
            wave_lgkm_wait();
            uint4 h = *reinterpret_cast<const uint4*>(&hist[lane * 4]);
            unsigned hb[4] = {h.x, h.y, h.z, h.w};
            unsigned s_local = hb[0] + hb[1] + hb[2] + hb[3];
            unsigned suf = s_local;                    // inclusive suffix-scan over lanes
            #pragma unroll
            for (int off = 1; off < 64; off <<= 1) {
                unsigned o = __shfl_down(suf, off);
                suf += (lane + off < 64) ? o : 0u;
            }
            unsigned acc_above = suf - s_local;        // elems in bins of higher lanes
            int foundc = -1; unsigned f_abv = 0;
            #pragma unroll
            for (int c = 3; c >= 0; --c) {             // descending bins within lane
                unsigned S = acc_above + hb[c];
                if (acc_above < kr && S >= kr) { foundc = c; f_abv = acc_above; }
                acc_above = S;
            }
            bool win = (foundc >= 0);
            unsigned long long bal = __ballot(win);
            int wl = __ffsll((long long)bal) - 1;      // exactly one winner lane
            unsigned np = win ? ((prefix << 8) | (unsigned)(lane * 4 + foundc)) : 0u;
            unsigned nk = win ? (kr - f_abv) : 0u;
            prefix = __shfl(np, wl);
            kr     = __shfl(nk, wl);
        }
        const unsigned tkey = prefix, krem = kr;

        int acc = 0;                                   // fixed-point, order-independent
        #pragma unroll
        for (int it = 0; it < 8; ++it) {
            unsigned k = keys[it];
            if ((lane + it * 64u) < CHI && k > tkey) {
                float w = key2f(k) + 1.0f;
                acc += (int)(w * w * SCALE + 0.5f);
            }
        }
        #pragma unroll
        for (int off = 32; off > 0; off >>= 1) acc += __shfl_down(acc, off);
        if (lane == 0) {
            float tv    = key2f(tkey) + 1.0f;
            float total = (float)acc * (1.0f / SCALE) + (float)krem * tv * tv;
            float pos   = rp[target];
            float pd    = pos - 1.0f;
            row_loss[row] = DELTA_W * pd * pd + total * (1.0f / (float)K_SEL);
        }
    } else {
        // ---- fallback: exact full-row radix (never taken for Gaussian bench data) ----
        for (int pass = 0; pass < 4; ++pass) {
            *reinterpret_cast<uint4*>(&hist[lane * 4]) = make_uint4(0, 0, 0, 0);
            wave_lgkm_wait();
            const int shift = 24 - 8 * pass;
            for (int it = 0; it < N / 64; ++it) {
                int i = lane + it * 64;
                unsigned k = f2key(rp[i]);
                if (i == target) k = 0u;
                bool m = (pass == 0) || ((k >> (shift + 8)) == prefix);
                if (m) atomicAdd(&hist[(k >> shift) & 0xFFu], 1u);
            }
            wave_lgkm_wait();
            uint4 h = *reinterpret_cast<const uint4*>(&hist[lane * 4]);
            unsigned hb[4] = {h.x, h.y, h.z, h.w};
            unsigned s_local = hb[0] + hb[1] + hb[2] + hb[3];
            unsigned suf = s_local;
            #pragma unroll
            for (int off = 1; off < 64; off <<= 1) {
                unsigned o = __shfl_down(suf, off);
                suf += (lane + off < 64) ? o : 0u;
            }
            unsigned acc_above = suf - s_local;
            int foundc = -1; unsigned f_abv = 0;
            #pragma unroll
            for (int c = 3; c >= 0; --c) {
                unsigned S = acc_above + hb[c];
                if (acc_above < kr && S >= kr) { foundc = c; f_abv = acc_above; }
                acc_above = S;
            }
            bool win = (foundc >= 0);
            unsigned long long bal = __ballot(win);
            int wl = __ffsll((long long)bal) - 1;
            unsigned np = win ? ((prefix << 8) | (unsigned)(lane * 4 + foundc)) : 0u;
            unsigned nk = win ? (kr - f_abv) : 0u;
            prefix = __shfl(np, wl);
            kr     = __shfl(nk, wl);
        }
        const unsigned tkey = prefix, krem = kr;

        int acc = 0;
        for (int it = 0; it < N / 64; ++it) {
            int i = lane + it * 64;
            unsigned k = f2key(rp[i]);
            if (i == target) k = 0u;
            if (k > tkey) { float w = key2f(k) + 1.0f; acc += (int)(w * w * SCALE + 0.5f); }
        }
        #pragma unroll
        for (int off = 32; off > 0; off >>= 1) acc += __shfl_down(acc, off);
        if (lane == 0) {
            float tv    = key2f(tkey) + 1.0f;
            float total = (float)acc * (1.0f / SCALE) + (float)krem * tv * tv;
            float pos   = rp[target];
            float pd    = pos - 1.0f;
            row_loss[row] = DELTA_W * pd * pd + total * (1.0f / (float)K_SEL);
        }
    }
}

__global__ __launch_bounds__(256) void final_reduce(
    const float* __restrict__ rl, float* __restrict__ out)
{
    int tid = threadIdx.x;
    float s = 0.0f;
    for (int i = tid; i < M; i += 256) s += rl[i];
    __shared__ float wp[4];
    int lane = tid & 63, wv = tid >> 6;
    #pragma unroll
    for (int off = 32; off > 0; off >>= 1) s += __shfl_down(s, off);
    if (lane == 0) wp[wv] = s;
    __syncthreads();
    if (tid == 0) out[0] = (wp[0] + wp[1] + wp[2] + wp[3]) / (float)M;
}

extern "C" void kernel_launch(void* const* d_in, const int* in_sizes, int n_in,
                              void* d_out, int out_size, void* d_ws, size_t ws_size,
                              hipStream_t stream) {
    const float* inp = (const float*)d_in[0];
    const int*   tgt = (const int*)d_in[1];
    float* out = (float*)d_out;

    unsigned* cnt  = (unsigned*)d_ws;                                 // 16 KiB
    unsigned* list = (unsigned*)((char*)d_ws + 16 * 1024);            // 8 MiB
    float* row_loss = (float*)((char*)d_ws + 16 * 1024 + (size_t)M * CAP * 4);

    hipMemsetAsync(cnt, 0, (size_t)M * sizeof(unsigned), stream);
    stream_candidates<<<M, NT, 0, stream>>>(inp, tgt, cnt, list);
    select_and_loss<<<M / 4, NT, 0, stream>>>(inp, tgt, cnt, list, row_loss);
    final_reduce<<<1, 256, 0, stream>>>(row_loss, out);
}

// Round 6
// 112.967 us; speedup vs baseline: 1.4147x; 1.4147x over previous
//
#include <hip/hip_runtime.h>

// inputs: [M=4096, N=16384] fp32 logits; targets: [M] int32; k = int(0.01*(N-1)) = 163
#define M        4096
#define N        16384
#define K_SEL    163
#define DELTA_W  5.0f
#define NT       256
#define CAP      512           // per-row candidate capacity (Gaussian: mean 373, sd 19)
#define SCALE    4096.0f       // fixed-point for hard-negative sum (order-independent)
#define GSCALE   1048576.0     // 2^20 fixed-point for the global row-loss sum
#define THRESH   2.0f          // E[count(x>=2)] = 373 per row; 11 sigma above K_SEL

typedef float vfloat4 __attribute__((ext_vector_type(4)));  // native vector: legal for nt-load

// Order-preserving float<->uint32 key (ascending float <-> ascending key)
__device__ __forceinline__ unsigned f2key(float x) {
    unsigned u = __float_as_uint(x);
    return u ^ ((unsigned)((int)u >> 31) | 0x80000000u);
}
__device__ __forceinline__ float key2f(unsigned k) {
    unsigned u = k ^ (~(unsigned)((int)k >> 31) | 0x80000000u);
    return __uint_as_float(u);
}
__device__ __forceinline__ void wave_lgkm_wait() {
    asm volatile("s_waitcnt lgkmcnt(0)" ::: "memory");
}

// ---------- Kernel A: nontemporal streaming filter, one block per row ----------
__global__ __launch_bounds__(NT) void stream_candidates(
    const float* __restrict__ inp, const int* __restrict__ tgt,
    unsigned* __restrict__ cnt, unsigned* __restrict__ list,
    unsigned long long* __restrict__ acc)
{
    const int row = blockIdx.x;
    const int tid = threadIdx.x;
    if (row == 0 && tid == 0) *acc = 0ull;   // A runs before B: safe zero, no memset node

    __shared__ unsigned s_list[CAP];         // 2 KiB
    __shared__ unsigned s_n;
    if (tid == 0) s_n = 0u;
    __syncthreads();

    const vfloat4* rp4 = reinterpret_cast<const vfloat4*>(inp + (size_t)row * N);
    const int target = tgt[row];

    for (int h = 0; h < 2; ++h) {
        vfloat4 v[8];                         // 8 nt loads in flight per batch
        #pragma unroll
        for (int u = 0; u < 8; ++u)
            v[u] = __builtin_nontemporal_load(&rp4[(h * 8 + u) * NT + tid]);
        #pragma unroll
        for (int u = 0; u < 8; ++u) {
            const int base = ((h * 8 + u) * NT + tid) * 4;
            float mx = fmaxf(fmaxf(v[u].x, v[u].y), fmaxf(v[u].z, v[u].w));
            if (mx >= THRESH) {
                #pragma unroll
                for (int j = 0; j < 4; ++j) {
                    float x = v[u][j];
                    if (x >= THRESH && (base + j) != target) {
                        unsigned idx = atomicAdd(&s_n, 1u);   // LDS atomic: fast return
                        if (idx < CAP) s_list[idx] = f2key(x);
                    }
                }
            }
        }
    }
    __syncthreads();
    const unsigned n = s_n;                  // exact count (increments never capped)
    if (tid == 0) cnt[row] = n;
    unsigned* rl = list + (size_t)row * CAP;
    const unsigned lim = (n < CAP) ? n : CAP;
    for (unsigned i = tid; i < lim; i += NT) rl[i] = s_list[i];   // coalesced
}

// ---------- Kernel B: wave-per-row radix select, zero __syncthreads ----------
__global__ __launch_bounds__(NT) void select_and_loss(
    const float* __restrict__ inp, const int* __restrict__ tgt,
    const unsigned* __restrict__ cnt, const unsigned* __restrict__ list,
    unsigned long long* __restrict__ acc)
{
    __shared__ unsigned hist_all[4][256];    // wave-private 1 KiB each
    const int lane = threadIdx.x & 63;
    const int wv   = threadIdx.x >> 6;
    const int row  = blockIdx.x * 4 + wv;
    unsigned* hist = hist_all[wv];
    const float* rp = inp + (size_t)row * N;
    const int target = tgt[row];
    const unsigned CHI = cnt[row];

    unsigned prefix = 0u, kr = K_SEL;
    float loss = 0.0f;
    bool have = false;

    if (CHI >= K_SEL && CHI <= CAP) {
        const unsigned* gl = list + (size_t)row * CAP;
        unsigned keys[8];
        #pragma unroll
        for (int it = 0; it < 8; ++it) {
            unsigned i = lane + it * 64u;
            keys[it] = (i < CHI) ? gl[i] : 0u;        // pad with min-key
        }
        for (int pass = 0; pass < 4; ++pass) {
            *reinterpret_cast<uint4*>(&hist[lane * 4]) = make_uint4(0, 0, 0, 0);
            wave_lgkm_wait();
            const int shift = 24 - 8 * pass;
            #pragma unroll
            for (int it = 0; it < 8; ++it) {
                unsigned k = keys[it];
                bool m = (lane + it * 64u < CHI) &&
                         (pass == 0 || (k >> (shift + 8)) == prefix);
                if (m) atomicAdd(&hist[(k >> shift) & 0xFFu], 1u);
            }
            wave_lgkm_wait();
            uint4 h = *reinterpret_cast<const uint4*>(&hist[lane * 4]);
            unsigned hb[4] = {h.x, h.y, h.z, h.w};
            unsigned s_local = hb[0] + hb[1] + hb[2] + hb[3];
            unsigned suf = s_local;                   // suffix-scan over lanes
            #pragma unroll
            for (int off = 1; off < 64; off <<= 1) {
                unsigned o = __shfl_down(suf, off);
                suf += (lane + off < 64) ? o : 0u;
            }
            unsigned acc_above = suf - s_local;
            int foundc = -1; unsigned f_abv = 0;
            #pragma unroll
            for (int c = 3; c >= 0; --c) {
                unsigned S = acc_above + hb[c];
                if (acc_above < kr && S >= kr) { foundc = c; f_abv = acc_above; }
                acc_above = S;
            }
            bool win = (foundc >= 0);
            unsigned long long bal = __ballot(win);
            int wl = __ffsll((long long)bal) - 1;
            unsigned np = win ? ((prefix << 8) | (unsigned)(lane * 4 + foundc)) : 0u;
            unsigned nk = win ? (kr - f_abv) : 0u;
            prefix = __shfl(np, wl);
            kr     = __shfl(nk, wl);
        }
        const unsigned tkey = prefix, krem = kr;

        int facc = 0;                                 // fixed-point, order-independent
        #pragma unroll
        for (int it = 0; it < 8; ++it) {
            unsigned k = keys[it];
            if ((lane + it * 64u) < CHI && k > tkey) {
                float w = key2f(k) + 1.0f;
                facc += (int)(w * w * SCALE + 0.5f);
            }
        }
        #pragma unroll
        for (int off = 32; off > 0; off >>= 1) facc += __shfl_down(facc, off);
        if (lane == 0) {
            float tv    = key2f(tkey) + 1.0f;
            float total = (float)facc * (1.0f / SCALE) + (float)krem * tv * tv;
            float pos   = rp[target];
            float pd    = pos - 1.0f;
            loss = DELTA_W * pd * pd + total * (1.0f / (float)K_SEL);
            have = true;
        }
    } else {
        // fallback: exact full-row radix (never taken for Gaussian bench data)
        for (int pass = 0; pass < 4; ++pass) {
            *reinterpret_cast<uint4*>(&hist[lane * 4]) = make_uint4(0, 0, 0, 0);
            wave_lgkm_wait();
            const int shift = 24 - 8 * pass;
            for (int it = 0; it < N / 64; ++it) {
                int i = lane + it * 64;
                unsigned k = f2key(rp[i]);
                if (i == target) k = 0u;
                bool m = (pass == 0) || ((k >> (shift + 8)) == prefix);
                if (m) atomicAdd(&hist[(k >> shift) & 0xFFu], 1u);
            }
            wave_lgkm_wait();
            uint4 h = *reinterpret_cast<const uint4*>(&hist[lane * 4]);
            unsigned hb[4] = {h.x, h.y, h.z, h.w};
            unsigned s_local = hb[0] + hb[1] + hb[2] + hb[3];
            unsigned suf = s_local;
            #pragma unroll
            for (int off = 1; off < 64; off <<= 1) {
                unsigned o = __shfl_down(suf, off);
                suf += (lane + off < 64) ? o : 0u;
            }
            unsigned acc_above = suf - s_local;
            int foundc = -1; unsigned f_abv = 0;
            #pragma unroll
            for (int c = 3; c >= 0; --c) {
                unsigned S = acc_above + hb[c];
                if (acc_above < kr && S >= kr) { foundc = c; f_abv = acc_above; }
                acc_above = S;
            }
            bool win = (foundc >= 0);
            unsigned long long bal = __ballot(win);
            int wl = __ffsll((long long)bal) - 1;
            unsigned np = win ? ((prefix << 8) | (unsigned)(lane * 4 + foundc)) : 0u;
            unsigned nk = win ? (kr - f_abv) : 0u;
            prefix = __shfl(np, wl);
            kr     = __shfl(nk, wl);
        }
        const unsigned tkey = prefix, krem = kr;

        int facc = 0;
        for (int it = 0; it < N / 64; ++it) {
            int i = lane + it * 64;
            unsigned k = f2key(rp[i]);
            if (i == target) k = 0u;
            if (k > tkey) { float w = key2f(k) + 1.0f; facc += (int)(w * w * SCALE + 0.5f); }
        }
        #pragma unroll
        for (int off = 32; off > 0; off >>= 1) facc += __shfl_down(facc, off);
        if (lane == 0) {
            float tv    = key2f(tkey) + 1.0f;
            float total = (float)facc * (1.0f / SCALE) + (float)krem * tv * tv;
            float pos   = rp[target];
            float pd    = pos - 1.0f;
            loss = DELTA_W * pd * pd + total * (1.0f / (float)K_SEL);
            have = true;
        }
    }

    // deterministic global mean: 2^20 fixed-point integer accumulate (loss >= 0)
    if (have) {
        unsigned long long q = (unsigned long long)((double)loss * GSCALE + 0.5);
        atomicAdd(acc, q);
    }
}

__global__ void finalize(const unsigned long long* __restrict__ acc,
                         float* __restrict__ out)
{
    if (threadIdx.x == 0)
        out[0] = (float)((double)(*acc) / (GSCALE * (double)M));
}

extern "C" void kernel_launch(void* const* d_in, const int* in_sizes, int n_in,
                              void* d_out, int out_size, void* d_ws, size_t ws_size,
                              hipStream_t stream) {
    const float* inp = (const float*)d_in[0];
    const int*   tgt = (const int*)d_in[1];
    float* out = (float*)d_out;

    unsigned* cnt  = (unsigned*)d_ws;                               // 16 KiB
    unsigned* list = (unsigned*)((char*)d_ws + 16 * 1024);          // 8 MiB
    unsigned long long* acc =
        (unsigned long long*)((char*)d_ws + 16 * 1024 + (size_t)M * CAP * 4);

    stream_candidates<<<M, NT, 0, stream>>>(inp, tgt, cnt, list, acc);
    select_and_loss<<<M / 4, NT, 0, stream>>>(inp, tgt, cnt, list, acc);
    finalize<<<1, 64, 0, stream>>>(acc, out);
}